// Round 18
// baseline (136.219 us; speedup 1.0000x reference)
//
#include <hip/hip_runtime.h>

typedef __attribute__((ext_vector_type(8))) short short8;   // 8 x bf16 bits
typedef __attribute__((ext_vector_type(4))) float f32x4;

#define SPB 4    // samples per group (1 per wave)
#define NG  8    // groups per block
// LDS element geometry (u16 units); row strides EVEN so pair-reads are b32-aligned
#define XP_S   400              // 20*20 padded input tile
#define A1_ROW 12               // 12 padded cols (even)
#define A1_CH  148              // 12*12 rows + 4 pad (oc-stride = 74 dwords)
#define A1_S   (12 * A1_CH)     // 1776 per sample
#define A2_S   200              // per-slot a2 stride (192 used; 400B, 16B-aligned)
#define A3_S   40               // per-slot a3 stride (32 used; 80B, 16B-aligned)

__device__ __forceinline__ float fast_tanh(float x) {
    float e = __builtin_amdgcn_exp2f(x * 2.8853900817779268f);
    return 1.0f - 2.0f * __builtin_amdgcn_rcpf(e + 1.0f);
}
__device__ __forceinline__ unsigned short f2bf(float f) {
    unsigned u = __builtin_bit_cast(unsigned, f);
    return (unsigned short)((u + 0x7FFF + ((u >> 16) & 1)) >> 16);
}
__device__ __forceinline__ float bf2f(unsigned short h) {
    return __builtin_bit_cast(float, (unsigned)h << 16);
}
__device__ __forceinline__ unsigned pack2bf(float lo, float hi) {
    return (unsigned)f2bf(lo) | ((unsigned)f2bf(hi) << 16);
}

// k-slot permutation sigma for 5x5 patches (shared by both MFMA operands):
// slot m=8*hi+j -> pair P=min(m>>1,14), ky=P/3, q=P%3, c=2q+(m&1).
// Real iff c<5; c==5 and m>=30 are zero-weight garbage slots.

// OPERAND-SWAPPED MFMAs (r16): mfma(patch, weights, acc) -> D row=position,
// col=oc -> paired b32 stores. a2/a3 slot convention (r8): slot s=(g&3)*4+wv.

// r18: amdgpu_waves_per_eu(4,4) pins the allocator to 128 VGPR (512/4).
// With (256,3) the compiler voluntarily targeted 6 waves/EU (=84 VGPR) and
// SPILLED any extra state (r17's aw3 -> scratch, r10's 64-VGPR disaster).
// LDS (39.9KB) caps residency at 4 blocks/CU anyway, so 4 waves/EU is the
// right target: no spills, full register headroom for scheduling.
__global__ __launch_bounds__(256)
__attribute__((amdgpu_waves_per_eu(4, 4)))
void lenet_mfma(
    const float* __restrict__ x,
    const float* __restrict__ w1, const float* __restrict__ b1,
    const float* __restrict__ w2, const float* __restrict__ b2,
    const float* __restrict__ w3, const float* __restrict__ b3,
    const float* __restrict__ ow, const float* __restrict__ ob,
    float* __restrict__ out)
{
    __shared__ __attribute__((aligned(16))) unsigned short wf3[6144];       // w3 A-frags
    __shared__ __attribute__((aligned(16))) unsigned short xp[SPB * XP_S];
    __shared__ __attribute__((aligned(16))) unsigned short a1[SPB * A1_S];
    __shared__ __attribute__((aligned(16))) unsigned short a2[16 * A2_S];   // [slot][oc*16+p]
    __shared__ __attribute__((aligned(16))) unsigned short a3[16 * A3_S];   // [slot][unit]
    __shared__ unsigned short b1s[768];                                     // bf16 biases
    __shared__ float b2s[192], b3s[32], obs[16];

    const int t = threadIdx.x;
    const int lane = t & 63, wv = t >> 6;
    const int hi = lane >> 4, col = lane & 15;

    // issue group-0 x load first (1 float4/thread; latency hides under setup)
    const float4* xg = (const float4*)(x + (size_t)blockIdx.x * NG * SPB * 256);
    float4 v0 = xg[t];

    // ---- per-lane pair offsets (u16 units) for the sigma gather ----
    int po1[4], po2[4];
    #pragma unroll
    for (int pp = 0; pp < 4; ++pp) {
        int P = 4 * hi + pp; if (P > 14) P = 14;
        int ky = P / 3, q = P - 3 * ky;
        po1[pp] = ky * 20 + 2 * q;
        po2[pp] = ky * A1_ROW + 2 * q;
    }

    // ---- aw1/aw2 in registers (52 VGPRs); sigma-packed ----
    short8 aw1;
    #pragma unroll
    for (int j = 0; j < 8; ++j) {
        int m = 8 * hi + j; float val = 0.f;
        if (m < 30 && col < 12) {
            int P = m >> 1, ky = P / 3, q = P - 3 * ky, c = 2 * q + (m & 1);
            if (c < 5) val = w1[col * 25 + ky * 5 + c];
        }
        aw1[j] = (short)f2bf(val);
    }
    short8 aw2[12];
    #pragma unroll
    for (int ic = 0; ic < 12; ++ic) {
        #pragma unroll
        for (int j = 0; j < 8; ++j) {
            int m = 8 * hi + j; float val = 0.f;
            if (m < 30 && col < 12) {
                int P = m >> 1, ky = P / 3, q = P - 3 * ky, c = 2 * q + (m & 1);
                if (c < 5) {
                    int oc = col, icw;
                    if (oc < 4)      icw = (ic < 8) ? ic : -1;
                    else if (oc < 8) icw = (ic >= 4) ? ic - 4 : -1;
                    else             icw = (ic < 4) ? ic : ((ic >= 8) ? ic - 4 : -1);
                    if (icw >= 0) val = w2[(oc * 8 + icw) * 25 + ky * 5 + c];
                }
            }
            aw2[ic][j] = (short)f2bf(val);
        }
    }
    short8 awo;   // out-layer A-frag (4 VGPRs), identity k-order
    #pragma unroll
    for (int j = 0; j < 8; ++j) {
        int k = 8 * hi + j;
        awo[j] = (short)f2bf((col < 10 && k < 30) ? ow[k * 10 + col] : 0.f);
    }

    // ---- wf3: w3 A-frags in LDS (once/block; registers spill — r17 lesson) ----
    for (int e = t; e < 768; e += 256) {
        int fi = e >> 6, le = e & 63;
        int rt = fi / 6, kt = fi - 6 * rt;
        int unit = rt * 16 + (le & 15);
        short8 v;
        #pragma unroll
        for (int j = 0; j < 8; ++j) {
            int k = kt * 32 + 8 * (le >> 4) + j;
            v[j] = (short)f2bf((unit < 30) ? w3[k * 30 + unit] : 0.f);
        }
        *((short8*)wf3 + e) = v;
    }

    // ---- fills: pad rings -1 (persist), a3 zero, biases ----
    {
        unsigned* xpw = (unsigned*)xp;
        for (int i = t; i < SPB * XP_S / 2; i += 256) xpw[i] = 0xBF80BF80u;
        unsigned* a1w = (unsigned*)a1;
        for (int i = t; i < SPB * A1_S / 2; i += 256) a1w[i] = 0xBF80BF80u;
        unsigned* a3w = (unsigned*)a3;
        for (int i = t; i < 16 * A3_S / 2; i += 256) a3w[i] = 0u;
        for (int i = t; i < 768; i += 256) b1s[i] = f2bf(b1[i]);
        if (t < 192) b2s[t] = b2[t];
        if (t < 32)  b3s[t] = (t < 30) ? b3[t] : 0.f;
        if (t < 16)  obs[t] = (t < 10) ? ob[t] : 0.f;
    }
    __syncthreads();

    const int q1 = 40 * (col >> 3) + 2 * (col & 7);   // H1 patch TL (u16), pos=col
    const int q2 = 24 * (col >> 2) + 2 * (col & 3);   // H2 patch TL (u16), pos=col
    const unsigned* xp32 = (const unsigned*)xp;
    const unsigned* a132 = (const unsigned*)a1;

    // ================= group loop =================
    #pragma unroll 1
    for (int g = 0; g < NG; ++g) {
        // ---- scatter own-sample x into padded LDS (same-wave prod/cons) ----
        {
            int r = lane >> 2, c4 = (lane & 3) * 4;
            int base = wv * XP_S + (2 + r) * 20 + (2 + c4);   // even
            unsigned* dst = (unsigned*)xp + (base >> 1);
            dst[0] = pack2bf(v0.x, v0.y);
            dst[1] = pack2bf(v0.z, v0.w);
        }
        if (g + 1 < NG) v0 = xg[(g + 1) * 256 + t];   // prefetch next group

        // ---- H1: A=patch, B=weights; lane owns 4 adjacent pixels of oc=col ----
        {
            int sbase = wv * XP_S + q1;
            #pragma unroll
            for (int pt = 0; pt < 4; ++pt) {
                int base = (sbase + pt * 80) >> 1;
                short8 a;
                #pragma unroll
                for (int pp = 0; pp < 4; ++pp) {
                    unsigned r = xp32[base + (po1[pp] >> 1)];
                    a[2 * pp]     = (short)(r & 0xffff);
                    a[2 * pp + 1] = (short)(r >> 16);
                }
                f32x4 acc = __builtin_amdgcn_mfma_f32_16x16x32_bf16(
                    a, aw1, (f32x4){0.f, 0.f, 0.f, 0.f}, 0, 0, 0);
                if (col < 12) {
                    int p0 = pt * 16 + 4 * hi;          // 4 adjacent positions
                    int oy = p0 >> 3, ox0 = p0 & 7;     // ox0 in {0,4}
                    int wbase = wv * A1_S + col * A1_CH + (2 + oy) * A1_ROW + (2 + ox0);
                    unsigned* d32 = (unsigned*)&a1[wbase];   // wbase even
                    float t0 = fast_tanh(acc[0] + bf2f(b1s[col * 64 + p0 + 0]));
                    float t1 = fast_tanh(acc[1] + bf2f(b1s[col * 64 + p0 + 1]));
                    float t2 = fast_tanh(acc[2] + bf2f(b1s[col * 64 + p0 + 2]));
                    float t3 = fast_tanh(acc[3] + bf2f(b1s[col * 64 + p0 + 3]));
                    d32[0] = pack2bf(t0, t1);
                    d32[1] = pack2bf(t2, t3);
                }
            }
        }

        // ---- H2: A=patch, B=weights; two independent 6-MFMA chains ----
        {
            int sbase = wv * A1_S + q2;
            f32x4 acc0 = {0.f, 0.f, 0.f, 0.f};
            f32x4 acc1 = {0.f, 0.f, 0.f, 0.f};
            #pragma unroll
            for (int ic = 0; ic < 6; ++ic) {
                int b0 = (sbase + ic * A1_CH) >> 1;
                int b1i = (sbase + (ic + 6) * A1_CH) >> 1;
                short8 p0, p1;
                #pragma unroll
                for (int pp = 0; pp < 4; ++pp) {
                    unsigned r0 = a132[b0 + (po2[pp] >> 1)];
                    unsigned r1 = a132[b1i + (po2[pp] >> 1)];
                    p0[2 * pp]     = (short)(r0 & 0xffff);
                    p0[2 * pp + 1] = (short)(r0 >> 16);
                    p1[2 * pp]     = (short)(r1 & 0xffff);
                    p1[2 * pp + 1] = (short)(r1 >> 16);
                }
                acc0 = __builtin_amdgcn_mfma_f32_16x16x32_bf16(p0, aw2[ic], acc0, 0, 0, 0);
                acc1 = __builtin_amdgcn_mfma_f32_16x16x32_bf16(p1, aw2[ic + 6], acc1, 0, 0, 0);
            }
            int sg = (g & 3) * 4 + wv;   // r8 slot convention
            if (col < 12) {
                int p0 = 4 * hi;                        // 4 adjacent positions
                int ib = sg * A2_S + col * 16 + p0;     // even
                unsigned* d32 = (unsigned*)&a2[ib];
                float v0o = fast_tanh(acc0[0] + acc1[0] + b2s[col * 16 + p0 + 0]);
                float v1o = fast_tanh(acc0[1] + acc1[1] + b2s[col * 16 + p0 + 1]);
                float v2o = fast_tanh(acc0[2] + acc1[2] + b2s[col * 16 + p0 + 2]);
                float v3o = fast_tanh(acc0[3] + acc1[3] + b2s[col * 16 + p0 + 3]);
                d32[0] = pack2bf(v0o, v1o);
                d32[1] = pack2bf(v2o, v3o);
            }
        }

        // ---- every 4 groups: H3 (waves 0,1; N=16 slots) + out (wave 0) ----
        if ((g & 3) == 3) {
            __syncthreads();   // a2 (16 slots) complete
            if (wv < 2) {
                int rt = wv;
                f32x4 acc = {0.f, 0.f, 0.f, 0.f};
                #pragma unroll
                for (int kt = 0; kt < 6; ++kt) {
                    short8 a = *((const short8*)wf3 + (rt * 6 + kt) * 64 + lane);
                    short8 b = *(const short8*)&a2[col * A2_S + kt * 32 + 8 * hi];
                    acc = __builtin_amdgcn_mfma_f32_16x16x32_bf16(a, b, acc, 0, 0, 0);
                }
                #pragma unroll
                for (int jj = 0; jj < 4; ++jj) {
                    int unit = rt * 16 + hi * 4 + jj;
                    if (unit < 30)
                        a3[col * A3_S + unit] = f2bf(fast_tanh(acc[jj] + b3s[unit]));
                }
            }
            __syncthreads();   // a3 cross-wave
            if (wv == 0) {
                short8 b = *(const short8*)&a3[col * A3_S + 8 * hi];
                f32x4 acc = __builtin_amdgcn_mfma_f32_16x16x32_bf16(
                    awo, b, (f32x4){0.f, 0.f, 0.f, 0.f}, 0, 0, 0);
                size_t sw = (size_t)blockIdx.x * (NG * SPB) + (g >> 2) * 16 + col;
                #pragma unroll
                for (int jj = 0; jj < 4; ++jj) {
                    int row = hi * 4 + jj;
                    if (row < 10)
                        out[sw * 10 + row] = fast_tanh(acc[jj] + obs[row]);
                }
            }
            __syncthreads();   // a2/a3 free for next window
        }
    }
}

extern "C" void kernel_launch(void* const* d_in, const int* in_sizes, int n_in,
                              void* d_out, int out_size, void* d_ws, size_t ws_size,
                              hipStream_t stream) {
    const float* x  = (const float*)d_in[0];
    const float* w1 = (const float*)d_in[1];
    const float* b1 = (const float*)d_in[2];
    const float* w2 = (const float*)d_in[3];
    const float* b2 = (const float*)d_in[4];
    const float* w3 = (const float*)d_in[5];
    const float* b3 = (const float*)d_in[6];
    const float* ow = (const float*)d_in[7];
    const float* ob = (const float*)d_in[8];
    float* out = (float*)d_out;

    const int B = in_sizes[0] / 256;   // 65536 samples
    lenet_mfma<<<dim3(B / (SPB * NG)), dim3(256), 0, stream>>>(
        x, w1, b1, w2, b2, w3, b3, ow, ob, out);
}

// Round 19
// 94.436 us; speedup vs baseline: 1.4424x; 1.4424x over previous
//
#include <hip/hip_runtime.h>

typedef __attribute__((ext_vector_type(8))) short short8;   // 8 x bf16 bits
typedef __attribute__((ext_vector_type(4))) float f32x4;

#define SPB 4    // samples per group (1 per wave)
#define NG  8    // groups per block
// LDS element geometry (u16 units); row strides EVEN so pair-reads are b32-aligned
#define XP_S   400              // 20*20 padded input tile
#define A1_ROW 12               // 12 padded cols (even)
#define A1_CH  148              // 12*12 rows + 4 pad (oc-stride = 74 dwords)
#define A1_S   (12 * A1_CH)     // 1776 per sample
#define A2_S   200              // per-slot a2 stride (192 used; 400B, 16B-aligned)
#define A3_S   40               // per-slot a3 stride (32 used; 80B, 16B-aligned)

__device__ __forceinline__ float fast_tanh(float x) {
    float e = __builtin_amdgcn_exp2f(x * 2.8853900817779268f);
    return 1.0f - 2.0f * __builtin_amdgcn_rcpf(e + 1.0f);
}
__device__ __forceinline__ unsigned short f2bf(float f) {
    unsigned u = __builtin_bit_cast(unsigned, f);
    return (unsigned short)((u + 0x7FFF + ((u >> 16) & 1)) >> 16);
}
__device__ __forceinline__ float bf2f(unsigned short h) {
    return __builtin_bit_cast(float, (unsigned)h << 16);
}
__device__ __forceinline__ unsigned pack2bf(float lo, float hi) {
    return (unsigned)f2bf(lo) | ((unsigned)f2bf(hi) << 16);
}

// k-slot permutation sigma for 5x5 patches (shared by both MFMA operands):
// slot m=8*hi+j -> pair P=min(m>>1,14), ky=P/3, q=P%3, c=2q+(m&1).
// Real iff c<5; c==5 and m>=30 are zero-weight garbage slots.

// OPERAND-SWAPPED MFMAs (r16): mfma(patch, weights, acc) -> D row=position,
// col=oc -> paired b32 stores. a2/a3 slot convention (r8): slot s=(g&3)*4+wv.

// Config: (256,3) / 84 VGPR / wf3 in LDS — the stable no-spill regime.
// r10/r17/r18 all proved: any attempt to raise occupancy or add register
// state makes the allocator spill (64-84 VGPR pin). Do not re-attempt.
// r19 delta vs r16: bias reads vectorized (uint2/float4) — fewer LDS instrs.
__global__ __launch_bounds__(256, 3) void lenet_mfma(
    const float* __restrict__ x,
    const float* __restrict__ w1, const float* __restrict__ b1,
    const float* __restrict__ w2, const float* __restrict__ b2,
    const float* __restrict__ w3, const float* __restrict__ b3,
    const float* __restrict__ ow, const float* __restrict__ ob,
    float* __restrict__ out)
{
    __shared__ __attribute__((aligned(16))) unsigned short wf3[6144];       // w3 A-frags
    __shared__ __attribute__((aligned(16))) unsigned short xp[SPB * XP_S];
    __shared__ __attribute__((aligned(16))) unsigned short a1[SPB * A1_S];
    __shared__ __attribute__((aligned(16))) unsigned short a2[16 * A2_S];   // [slot][oc*16+p]
    __shared__ __attribute__((aligned(16))) unsigned short a3[16 * A3_S];   // [slot][unit]
    __shared__ __attribute__((aligned(8)))  unsigned short b1s[768];        // bf16 biases
    __shared__ __attribute__((aligned(16))) float b2s[192];
    __shared__ __attribute__((aligned(16))) float b3s[32];
    __shared__ __attribute__((aligned(16))) float obs[16];

    const int t = threadIdx.x;
    const int lane = t & 63, wv = t >> 6;
    const int hi = lane >> 4, col = lane & 15;

    // issue group-0 x load first (1 float4/thread; latency hides under setup)
    const float4* xg = (const float4*)(x + (size_t)blockIdx.x * NG * SPB * 256);
    float4 v0 = xg[t];

    // ---- per-lane pair offsets (u16 units) for the sigma gather ----
    int po1[4], po2[4];
    #pragma unroll
    for (int pp = 0; pp < 4; ++pp) {
        int P = 4 * hi + pp; if (P > 14) P = 14;
        int ky = P / 3, q = P - 3 * ky;
        po1[pp] = ky * 20 + 2 * q;
        po2[pp] = ky * A1_ROW + 2 * q;
    }

    // ---- aw1/aw2 in registers (52 VGPRs); sigma-packed ----
    short8 aw1;
    #pragma unroll
    for (int j = 0; j < 8; ++j) {
        int m = 8 * hi + j; float val = 0.f;
        if (m < 30 && col < 12) {
            int P = m >> 1, ky = P / 3, q = P - 3 * ky, c = 2 * q + (m & 1);
            if (c < 5) val = w1[col * 25 + ky * 5 + c];
        }
        aw1[j] = (short)f2bf(val);
    }
    short8 aw2[12];
    #pragma unroll
    for (int ic = 0; ic < 12; ++ic) {
        #pragma unroll
        for (int j = 0; j < 8; ++j) {
            int m = 8 * hi + j; float val = 0.f;
            if (m < 30 && col < 12) {
                int P = m >> 1, ky = P / 3, q = P - 3 * ky, c = 2 * q + (m & 1);
                if (c < 5) {
                    int oc = col, icw;
                    if (oc < 4)      icw = (ic < 8) ? ic : -1;
                    else if (oc < 8) icw = (ic >= 4) ? ic - 4 : -1;
                    else             icw = (ic < 4) ? ic : ((ic >= 8) ? ic - 4 : -1);
                    if (icw >= 0) val = w2[(oc * 8 + icw) * 25 + ky * 5 + c];
                }
            }
            aw2[ic][j] = (short)f2bf(val);
        }
    }
    short8 awo;   // out-layer A-frag (4 VGPRs), identity k-order
    #pragma unroll
    for (int j = 0; j < 8; ++j) {
        int k = 8 * hi + j;
        awo[j] = (short)f2bf((col < 10 && k < 30) ? ow[k * 10 + col] : 0.f);
    }

    // ---- wf3: w3 A-frags in LDS (once/block; registers spill — r17 lesson) ----
    for (int e = t; e < 768; e += 256) {
        int fi = e >> 6, le = e & 63;
        int rt = fi / 6, kt = fi - 6 * rt;
        int unit = rt * 16 + (le & 15);
        short8 v;
        #pragma unroll
        for (int j = 0; j < 8; ++j) {
            int k = kt * 32 + 8 * (le >> 4) + j;
            v[j] = (short)f2bf((unit < 30) ? w3[k * 30 + unit] : 0.f);
        }
        *((short8*)wf3 + e) = v;
    }

    // ---- fills: pad rings -1 (persist), a3 zero, biases ----
    {
        unsigned* xpw = (unsigned*)xp;
        for (int i = t; i < SPB * XP_S / 2; i += 256) xpw[i] = 0xBF80BF80u;
        unsigned* a1w = (unsigned*)a1;
        for (int i = t; i < SPB * A1_S / 2; i += 256) a1w[i] = 0xBF80BF80u;
        unsigned* a3w = (unsigned*)a3;
        for (int i = t; i < 16 * A3_S / 2; i += 256) a3w[i] = 0u;
        for (int i = t; i < 768; i += 256) b1s[i] = f2bf(b1[i]);
        if (t < 192) b2s[t] = b2[t];
        if (t < 32)  b3s[t] = (t < 30) ? b3[t] : 0.f;
        if (t < 16)  obs[t] = (t < 10) ? ob[t] : 0.f;
    }
    __syncthreads();

    const int q1 = 40 * (col >> 3) + 2 * (col & 7);   // H1 patch TL (u16), pos=col
    const int q2 = 24 * (col >> 2) + 2 * (col & 3);   // H2 patch TL (u16), pos=col
    const unsigned* xp32 = (const unsigned*)xp;
    const unsigned* a132 = (const unsigned*)a1;

    // ================= group loop =================
    #pragma unroll 1
    for (int g = 0; g < NG; ++g) {
        // ---- scatter own-sample x into padded LDS (same-wave prod/cons) ----
        {
            int r = lane >> 2, c4 = (lane & 3) * 4;
            int base = wv * XP_S + (2 + r) * 20 + (2 + c4);   // even
            unsigned* dst = (unsigned*)xp + (base >> 1);
            dst[0] = pack2bf(v0.x, v0.y);
            dst[1] = pack2bf(v0.z, v0.w);
        }
        if (g + 1 < NG) v0 = xg[(g + 1) * 256 + t];   // prefetch next group

        // ---- H1: A=patch, B=weights; lane owns 4 adjacent pixels of oc=col ----
        {
            int sbase = wv * XP_S + q1;
            #pragma unroll
            for (int pt = 0; pt < 4; ++pt) {
                int base = (sbase + pt * 80) >> 1;
                short8 a;
                #pragma unroll
                for (int pp = 0; pp < 4; ++pp) {
                    unsigned r = xp32[base + (po1[pp] >> 1)];
                    a[2 * pp]     = (short)(r & 0xffff);
                    a[2 * pp + 1] = (short)(r >> 16);
                }
                f32x4 acc = __builtin_amdgcn_mfma_f32_16x16x32_bf16(
                    a, aw1, (f32x4){0.f, 0.f, 0.f, 0.f}, 0, 0, 0);
                if (col < 12) {
                    int p0 = pt * 16 + 4 * hi;          // 4 adjacent positions
                    int oy = p0 >> 3, ox0 = p0 & 7;     // ox0 in {0,4}
                    int wbase = wv * A1_S + col * A1_CH + (2 + oy) * A1_ROW + (2 + ox0);
                    unsigned* d32 = (unsigned*)&a1[wbase];   // wbase even
                    uint2 bb = *(const uint2*)&b1s[col * 64 + p0];   // 4 bf16, b64
                    float t0 = fast_tanh(acc[0] + bf2f((unsigned short)(bb.x & 0xffff)));
                    float t1 = fast_tanh(acc[1] + bf2f((unsigned short)(bb.x >> 16)));
                    float t2 = fast_tanh(acc[2] + bf2f((unsigned short)(bb.y & 0xffff)));
                    float t3 = fast_tanh(acc[3] + bf2f((unsigned short)(bb.y >> 16)));
                    d32[0] = pack2bf(t0, t1);
                    d32[1] = pack2bf(t2, t3);
                }
            }
        }

        // ---- H2: A=patch, B=weights; two independent 6-MFMA chains ----
        {
            int sbase = wv * A1_S + q2;
            f32x4 acc0 = {0.f, 0.f, 0.f, 0.f};
            f32x4 acc1 = {0.f, 0.f, 0.f, 0.f};
            #pragma unroll
            for (int ic = 0; ic < 6; ++ic) {
                int b0 = (sbase + ic * A1_CH) >> 1;
                int b1i = (sbase + (ic + 6) * A1_CH) >> 1;
                short8 p0v, p1v;
                #pragma unroll
                for (int pp = 0; pp < 4; ++pp) {
                    unsigned r0 = a132[b0 + (po2[pp] >> 1)];
                    unsigned r1 = a132[b1i + (po2[pp] >> 1)];
                    p0v[2 * pp]     = (short)(r0 & 0xffff);
                    p0v[2 * pp + 1] = (short)(r0 >> 16);
                    p1v[2 * pp]     = (short)(r1 & 0xffff);
                    p1v[2 * pp + 1] = (short)(r1 >> 16);
                }
                acc0 = __builtin_amdgcn_mfma_f32_16x16x32_bf16(p0v, aw2[ic], acc0, 0, 0, 0);
                acc1 = __builtin_amdgcn_mfma_f32_16x16x32_bf16(p1v, aw2[ic + 6], acc1, 0, 0, 0);
            }
            int sg = (g & 3) * 4 + wv;   // r8 slot convention
            if (col < 12) {
                int p0 = 4 * hi;                        // 4 adjacent positions
                int ib = sg * A2_S + col * 16 + p0;     // even
                unsigned* d32 = (unsigned*)&a2[ib];
                float4 b4 = *(const float4*)&b2s[col * 16 + p0];   // b128
                float v0o = fast_tanh(acc0[0] + acc1[0] + b4.x);
                float v1o = fast_tanh(acc0[1] + acc1[1] + b4.y);
                float v2o = fast_tanh(acc0[2] + acc1[2] + b4.z);
                float v3o = fast_tanh(acc0[3] + acc1[3] + b4.w);
                d32[0] = pack2bf(v0o, v1o);
                d32[1] = pack2bf(v2o, v3o);
            }
        }

        // ---- every 4 groups: H3 (waves 0,1; N=16 slots) + out (wave 0) ----
        if ((g & 3) == 3) {
            __syncthreads();   // a2 (16 slots) complete
            if (wv < 2) {
                int rt = wv;
                f32x4 acc = {0.f, 0.f, 0.f, 0.f};
                #pragma unroll
                for (int kt = 0; kt < 6; ++kt) {
                    short8 a = *((const short8*)wf3 + (rt * 6 + kt) * 64 + lane);
                    short8 b = *(const short8*)&a2[col * A2_S + kt * 32 + 8 * hi];
                    acc = __builtin_amdgcn_mfma_f32_16x16x32_bf16(a, b, acc, 0, 0, 0);
                }
                float4 b34 = *(const float4*)&b3s[rt * 16 + 4 * hi];   // b128
                #pragma unroll
                for (int jj = 0; jj < 4; ++jj) {
                    int unit = rt * 16 + hi * 4 + jj;
                    float bj = (jj == 0) ? b34.x : (jj == 1) ? b34.y : (jj == 2) ? b34.z : b34.w;
                    if (unit < 30)
                        a3[col * A3_S + unit] = f2bf(fast_tanh(acc[jj] + bj));
                }
            }
            __syncthreads();   // a3 cross-wave
            if (wv == 0) {
                short8 b = *(const short8*)&a3[col * A3_S + 8 * hi];
                f32x4 acc = __builtin_amdgcn_mfma_f32_16x16x32_bf16(
                    awo, b, (f32x4){0.f, 0.f, 0.f, 0.f}, 0, 0, 0);
                float4 ob4 = *(const float4*)&obs[4 * hi];             // b128
                size_t sw = (size_t)blockIdx.x * (NG * SPB) + (g >> 2) * 16 + col;
                #pragma unroll
                for (int jj = 0; jj < 4; ++jj) {
                    int row = hi * 4 + jj;
                    float bj = (jj == 0) ? ob4.x : (jj == 1) ? ob4.y : (jj == 2) ? ob4.z : ob4.w;
                    if (row < 10)
                        out[sw * 10 + row] = fast_tanh(acc[jj] + bj);
                }
            }
            __syncthreads();   // a2/a3 free for next window
        }
    }
}

extern "C" void kernel_launch(void* const* d_in, const int* in_sizes, int n_in,
                              void* d_out, int out_size, void* d_ws, size_t ws_size,
                              hipStream_t stream) {
    const float* x  = (const float*)d_in[0];
    const float* w1 = (const float*)d_in[1];
    const float* b1 = (const float*)d_in[2];
    const float* w2 = (const float*)d_in[3];
    const float* b2 = (const float*)d_in[4];
    const float* w3 = (const float*)d_in[5];
    const float* b3 = (const float*)d_in[6];
    const float* ow = (const float*)d_in[7];
    const float* ob = (const float*)d_in[8];
    float* out = (float*)d_out;

    const int B = in_sizes[0] / 256;   // 65536 samples
    lenet_mfma<<<dim3(B / (SPB * NG)), dim3(256), 0, stream>>>(
        x, w1, b1, w2, b2, w3, b3, ow, ob, out);
}